// Round 7
// baseline (2745.516 us; speedup 1.0000x reference)
//
#include <hip/hip_runtime.h>
#include <math.h>

#define UNITS 1024
#define FEAT 128
#define TSEQ 48
#define BATCH 2048
#define OUT_STEPS 24
#define N4 4096

typedef unsigned short ushort;
typedef __attribute__((ext_vector_type(8))) short bf16x8;
typedef __attribute__((ext_vector_type(4))) float f32x4;

__device__ __forceinline__ ushort f2bf(float f) {
  unsigned u = __float_as_uint(f);
  unsigned r = (u + 0x7FFF + ((u >> 16) & 1)) >> 16;
  return (ushort)r;
}
__device__ __forceinline__ float sigm(float x) { return 1.0f / (1.0f + __expf(-x)); }
__device__ __forceinline__ float tanh_f(float x) { return 1.0f - 2.0f / (1.0f + __expf(2.0f * x)); }

// ============ fragment-order conventions (16x16x32 MFMA, verified m89) ============
// A-frag (M=16 rows, K=32): element (row, k) -> lane = ((k>>3)&3)*16 + (row&15), e = k&7
// B-frag (K=32, N=16 cols): element (k, col) -> lane = ((k>>3)&3)*16 + (col&15), e = k&7
// Storage: frag-major arrays F[frag][kc][64][8] (1 KB per (frag,kc) slice -> one
// fully-coalesced global_load_dwordx4 per wave).

// ---------------- prep kernels ----------------

// inputs [B][T][F] fp32 -> XF [T][128 rf][4 kc][64][8] bf16 (A-fragment order)
__global__ __launch_bounds__(256)
void convert_inputs_kernel(const float* __restrict__ in, ushort* __restrict__ XF) {
  const int g = blockIdx.x * 256 + threadIdx.x;   // ((t*128+rf)*4+kc)*64 + lane
  const int lane = g & 63;
  const int kc = (g >> 6) & 3;
  const int rf = (g >> 8) & 127;
  const int t = g >> 15;
  const int b = rf * 16 + (lane & 15);
  const int f = kc * 32 + ((lane >> 4) & 3) * 8;
  const float* src = &in[((size_t)b * TSEQ + t) * FEAT + f];
  const float4 v0 = *reinterpret_cast<const float4*>(src);
  const float4 v1 = *reinterpret_cast<const float4*>(src + 4);
  ushort v[8];
  v[0] = f2bf(v0.x); v[1] = f2bf(v0.y); v[2] = f2bf(v0.z); v[3] = f2bf(v0.w);
  v[4] = f2bf(v1.x); v[5] = f2bf(v1.y); v[6] = f2bf(v1.z); v[7] = f2bf(v1.w);
  *reinterpret_cast<bf16x8*>(&XF[(size_t)g * 8]) = *reinterpret_cast<bf16x8*>(v);
}

// kernel [128][4096] + recurrent [1024][4096] fp32 -> WpF [256 cf][36 kc][64][8] bf16
// (B-fragment order). Gate-permuted col: np = cf*16 + (lane&15) = ugrp*64+gate*16+u16,
// source col = gate*1024 + ugrp*16 + u16. k = kc*32 + ((lane>>4)&3)*8 + e; k<128 -> kW.
__global__ __launch_bounds__(256)
void prep_wF_kernel(const float* __restrict__ kW, const float* __restrict__ rW,
                    ushort* __restrict__ WpF) {
  const int g = blockIdx.x * 256 + threadIdx.x;   // (cf*36 + kc)*64 + lane
  const int lane = g & 63;
  const int kc = (g >> 6) % 36;
  const int cf = g / 2304;
  const int np = cf * 16 + (lane & 15);
  const int kbase = kc * 32 + ((lane >> 4) & 3) * 8;
  const int u16 = np & 15, gg = (np >> 4) & 3, ugrp = np >> 6;
  const int nsrc = gg * 1024 + ugrp * 16 + u16;
  ushort v[8];
#pragma unroll
  for (int e = 0; e < 8; ++e) {
    const int k = kbase + e;
    const float f = (k < FEAT) ? kW[(size_t)k * N4 + nsrc] : rW[(size_t)(k - FEAT) * N4 + nsrc];
    v[e] = f2bf(f);
  }
  *reinterpret_cast<bf16x8*>(&WpF[(size_t)g * 8]) = *reinterpret_cast<bf16x8*>(v);
}

// dense_w [1024][128] fp32 -> WdtF [8 cf][32 kc][64][8] bf16 (B-fragment order)
__global__ __launch_bounds__(256)
void prep_wdF_kernel(const float* __restrict__ dw, ushort* __restrict__ WdtF) {
  const int g = blockIdx.x * 256 + threadIdx.x;   // (cf*32+kc)*64 + lane, 16384 total
  const int lane = g & 63;
  const int kc = (g >> 6) & 31;
  const int cf = g >> 11;
  const int col = cf * 16 + (lane & 15);
  const int kb = kc * 32 + ((lane >> 4) & 3) * 8;
  ushort v[8];
#pragma unroll
  for (int e = 0; e < 8; ++e) v[e] = f2bf(dw[(size_t)(kb + e) * FEAT + col]);
  *reinterpret_cast<bf16x8*>(&WdtF[(size_t)g * 8]) = *reinterpret_cast<bf16x8*>(v);
}

// b2[n] = bias[n] + sum_f db[f] * W[f][n]   (original gate order)
__global__ __launch_bounds__(256)
void prep_b2_kernel(const float* __restrict__ bias, const float* __restrict__ db,
                    const float* __restrict__ W, float* __restrict__ b2) {
  const int n = blockIdx.x * 256 + threadIdx.x;
  float s = bias[n];
#pragma unroll 8
  for (int f = 0; f < FEAT; ++f) s += db[f] * W[(size_t)f * N4 + n];
  b2[n] = s;
}

// U' = Wd@W + U -> Wp2F [256 cf][32 kc][64][8] bf16 (B-fragment order)
__global__ __launch_bounds__(256)
void prep_u_kernel(const float* __restrict__ dw,   // [1024][128]
                   const float* __restrict__ W,    // [128][4096]
                   const float* __restrict__ rW,   // [1024][4096]
                   ushort* __restrict__ Wp2F) {
  __shared__ float sWd[64][132];   // [k_local][f]
  __shared__ float sW[128][68];    // [f][n'_local]
  const int tid = threadIdx.x;
  const int ugrp = blockIdx.x;
  const int k0 = blockIdx.y * 64;
  const int n0 = ugrp * 64;

#pragma unroll
  for (int p = 0; p < 8; ++p) {
    const int li = p * 256 + tid;
    const int kk = li >> 5, f4 = (li & 31) * 4;
    *reinterpret_cast<float4*>(&sWd[kk][f4]) =
        *reinterpret_cast<const float4*>(&dw[(size_t)(k0 + kk) * FEAT + f4]);
  }
#pragma unroll
  for (int p = 0; p < 32; ++p) {
    const int li = p * 256 + tid;
    const int f = li >> 6, nn = li & 63;
    const int u16 = nn & 15, gg = (nn >> 4) & 3;
    const int nsrc = gg * 1024 + ugrp * 16 + u16;
    sW[f][nn] = W[(size_t)f * N4 + nsrc];
  }
  __syncthreads();

  const int tx = tid & 15;
  const int ty = tid >> 4;
  float acc[4][4] = {};
  for (int f = 0; f < 128; ++f) {
    float a[4], b[4];
#pragma unroll
    for (int j = 0; j < 4; ++j) a[j] = sWd[tx * 4 + j][f];
#pragma unroll
    for (int i = 0; i < 4; ++i) b[i] = sW[f][ty * 4 + i];
#pragma unroll
    for (int i = 0; i < 4; ++i)
#pragma unroll
      for (int j = 0; j < 4; ++j) acc[i][j] += a[j] * b[i];
  }

#pragma unroll
  for (int i = 0; i < 4; ++i) {
    const int np = n0 + ty * 4 + i;
    const int u16 = np & 15, gg = (np >> 4) & 3;
    const int nsrc = gg * 1024 + ugrp * 16 + u16;
    const int cf = np >> 4;
#pragma unroll
    for (int j = 0; j < 4; ++j) {
      const int k = k0 + tx * 4 + j;
      const float v = rW[(size_t)k * N4 + nsrc] + acc[i][j];
      const int kc = k >> 5, lane = ((k >> 3) & 3) * 16 + (np & 15), e = k & 7;
      Wp2F[(((size_t)cf * 32 + kc) * 64 + lane) * 8 + e] = f2bf(v);
    }
  }
}

// ---------------- fused LSTM step: barrier-free, LDS-free register GEMM ----------------
// 128x128 tile, 4 waves (64x64 each). A (x/h fragment-order) and B (weights
// fragment-order) load straight global->VGPR, fully coalesced. No LDS, no barriers:
// the compiler schedules loads/waits precisely; 8 waves/CU hide L2 latency.
// KCH: # of 32-k chunks from H; NKS: B kc-stride; HASX: x-part; ZC: c==h==0 (t=0).
template<int KCH, int NKS, bool HASX, bool ZC>
__global__ __launch_bounds__(256, 2)
void lstm_step_kernel(const ushort* __restrict__ XF,    // [128 rf][4][512] (this t)
                      const ushort* __restrict__ HF,    // [128 rf][32][512]
                      const ushort* __restrict__ WF,    // [256 cf][NKS][512]
                      const float* __restrict__ bias,   // [4096] fp32, orig gate order
                      float* __restrict__ CF,           // fragment-ordered c state
                      ushort* __restrict__ HoutF) {     // [128 rf][32][512]
  const int bid = blockIdx.x;
  const int wg = (bid & 7) * 64 + (bid >> 3);   // bijective XCD chunk swizzle (512%8==0)
  const int bx = wg & 15, by = wg >> 4;

  const int tid = threadIdx.x;
  const int wid = tid >> 6;
  const int l = tid & 63;
  const int wr = wid >> 1, wc = wid & 1;
  const int l15 = l & 15, kg = l >> 4;

  const int rfb = bx * 8 + wr * 4;   // A row-frag base
  const int cfb = by * 8 + wc * 4;   // B col-frag base

  f32x4 acc[4][4] = {};

  if (HASX) {
#pragma unroll
    for (int kc = 0; kc < 4; ++kc) {
      bf16x8 av[4], bv[4];
#pragma unroll
      for (int m = 0; m < 4; ++m)
        av[m] = *reinterpret_cast<const bf16x8*>(
            XF + (((size_t)(rfb + m) * 4 + kc) * 64 + l) * 8);
#pragma unroll
      for (int n = 0; n < 4; ++n)
        bv[n] = *reinterpret_cast<const bf16x8*>(
            WF + (((size_t)(cfb + n) * NKS + kc) * 64 + l) * 8);
#pragma unroll
      for (int m = 0; m < 4; ++m)
#pragma unroll
        for (int n = 0; n < 4; ++n)
          acc[m][n] = __builtin_amdgcn_mfma_f32_16x16x32_bf16(av[m], bv[n], acc[m][n], 0, 0, 0);
    }
  }

#pragma unroll 4
  for (int kc = 0; kc < KCH; ++kc) {
    bf16x8 av[4], bv[4];
#pragma unroll
    for (int m = 0; m < 4; ++m)
      av[m] = *reinterpret_cast<const bf16x8*>(
          HF + (((size_t)(rfb + m) * 32 + kc) * 64 + l) * 8);
#pragma unroll
    for (int n = 0; n < 4; ++n)
      bv[n] = *reinterpret_cast<const bf16x8*>(
          WF + (((size_t)(cfb + n) * NKS + (HASX ? 4 : 0) + kc) * 64 + l) * 8);
#pragma unroll
    for (int m = 0; m < 4; ++m)
#pragma unroll
      for (int n = 0; n < 4; ++n)
        acc[m][n] = __builtin_amdgcn_mfma_f32_16x16x32_bf16(av[m], bv[n], acc[m][n], 0, 0, 0);
  }

  // ---- epilogue: gates + state update; h written in A-fragment order ----
  const int U = by * 2 + wc;            // unit-group 0..63
  const int unit = U * 16 + l15;
  const float bi = bias[unit];
  const float bf_ = bias[1024 + unit];
  const float bg = bias[2048 + unit];
  const float bo = bias[3072 + unit];

  const int Rr = bx * 2 + wr;
  const size_t cfbase = (((size_t)Rr * 64 + U) * 64 + l) * 16;
  const int kcu = unit >> 5;                 // h-fragment kc of this unit
  const int lxb = ((unit >> 3) & 3) * 16;    // h-fragment lane base
  const int eu = unit & 7;                   // h-fragment elem

  f32x4 cpre[4];
  if (!ZC) {
#pragma unroll
    for (int m = 0; m < 4; ++m)
      cpre[m] = *reinterpret_cast<const f32x4*>(CF + cfbase + m * 4);
  }

#pragma unroll
  for (int m = 0; m < 4; ++m) {
    const size_t hfrag = (((size_t)(rfb + m) * 32 + kcu) * 64);
    f32x4 cout;
#pragma unroll
    for (int j = 0; j < 4; ++j) {
      const float i_ = sigm(acc[m][0][j] + bi);
      const float f_ = sigm(acc[m][1][j] + bf_);
      const float g_ = tanh_f(acc[m][2][j] + bg);
      const float o_ = sigm(acc[m][3][j] + bo);
      const float cn = ZC ? (i_ * g_) : (f_ * cpre[m][j] + i_ * g_);
      cout[j] = cn;
      HoutF[(hfrag + lxb + kg * 4 + j) * 8 + eu] = f2bf(o_ * tanh_f(cn));
    }
    *reinterpret_cast<f32x4*>(CF + cfbase + m * 4) = cout;
  }
}

// ---------------- batched dense (register-direct): out = HallF @ Wd + db ----------------
// M = 24*2048 rows (HallF rf 0..3071), N = 128, K = 1024. Block 128x128, 4 waves.
__global__ __launch_bounds__(256, 2)
void dense_allF_kernel(const ushort* __restrict__ HallF,  // [3072 rf][32][512]
                       const ushort* __restrict__ WdtF,   // [8 cf][32][512]
                       const float* __restrict__ db,
                       float* __restrict__ out) {         // [2048][24][128] fp32
  const int bid = blockIdx.x;    // 384
  const int tid = threadIdx.x;
  const int wid = tid >> 6;
  const int l = tid & 63;
  const int wr = wid >> 1, wc = wid & 1;
  const int l15 = l & 15, kg = l >> 4;
  const int rfb = bid * 8 + wr * 4;
  const int cfb = wc * 4;

  f32x4 acc[4][4] = {};

#pragma unroll 4
  for (int kc = 0; kc < 32; ++kc) {
    bf16x8 av[4], bv[4];
#pragma unroll
    for (int m = 0; m < 4; ++m)
      av[m] = *reinterpret_cast<const bf16x8*>(
          HallF + (((size_t)(rfb + m) * 32 + kc) * 64 + l) * 8);
#pragma unroll
    for (int n = 0; n < 4; ++n)
      bv[n] = *reinterpret_cast<const bf16x8*>(
          WdtF + (((size_t)(cfb + n) * 32 + kc) * 64 + l) * 8);
#pragma unroll
    for (int m = 0; m < 4; ++m)
#pragma unroll
      for (int n = 0; n < 4; ++n)
        acc[m][n] = __builtin_amdgcn_mfma_f32_16x16x32_bf16(av[m], bv[n], acc[m][n], 0, 0, 0);
  }

#pragma unroll
  for (int n = 0; n < 4; ++n) {
    const int col = (cfb + n) * 16 + l15;
    const float bb = db[col];
#pragma unroll
    for (int m = 0; m < 4; ++m) {
#pragma unroll
      for (int j = 0; j < 4; ++j) {
        const int row = bid * 128 + wr * 64 + m * 16 + kg * 4 + j;
        const int s = row >> 11, b = row & 2047;
        out[((size_t)b * OUT_STEPS + s) * FEAT + col] = acc[m][n][j] + bb;
      }
    }
  }
}

// ---------------- launch ----------------
extern "C" void kernel_launch(void* const* d_in, const int* in_sizes, int n_in,
                              void* d_out, int out_size, void* d_ws, size_t ws_size,
                              hipStream_t stream) {
  const float* inputs  = (const float*)d_in[0];
  const float* kernelW = (const float*)d_in[1];
  const float* recW    = (const float*)d_in[2];
  const float* bias    = (const float*)d_in[3];
  const float* dw      = (const float*)d_in[4];
  const float* db      = (const float*)d_in[5];
  float* out = (float*)d_out;

  char* ws = (char*)d_ws;
  float*  CF    = (float*)ws;                                   // 8 MB
  ushort* XF    = (ushort*)(ws + 8388608);                      // 24 MB (warmup only)
  ushort* Wp2F  = XF;                                           // 8 MB, aliases XF
  ushort* HbF0  = (ushort*)(ws + 33554432);                     // 4 MB
  ushort* HbF1  = (ushort*)(ws + 37748736);                     // 4 MB
  ushort* WpF   = (ushort*)(ws + 41943040);                     // 9 MB
  ushort* WdtF  = (ushort*)(ws + 51380224);                     // 256 KB
  float*  b2    = (float*)(ws + 51642368);                      // 16 KB
  ushort* HallF = (ushort*)(ws + 51658752);                     // 96 MB: [24][128][32][512]
  ushort* HbF[2] = {HbF0, HbF1};
  const size_t HSLOT = (size_t)128 * 32 * 512;                  // ushorts per h snapshot
  const size_t XSLOT = (size_t)128 * 4 * 512;                   // ushorts per x timestep

  convert_inputs_kernel<<<TSEQ * 128 * 4 * 64 / 256, 256, 0, stream>>>(inputs, XF);
  prep_wF_kernel<<<256 * 36 * 64 / 256, 256, 0, stream>>>(kernelW, recW, WpF);
  prep_wdF_kernel<<<8 * 32 * 64 / 256, 256, 0, stream>>>(dw, WdtF);
  prep_b2_kernel<<<N4 / 256, 256, 0, stream>>>(bias, db, kernelW, b2);

  // t = 0: c = h = 0 -> x-part only, no C read, no memsets.
  lstm_step_kernel<0, 36, true, true><<<512, 256, 0, stream>>>(
      XF, HbF0 /*unused*/, WpF, bias, CF, HbF1);
  int cur = 1;
  for (int t = 1; t < TSEQ; ++t) {
    ushort* hout = (t == TSEQ - 1) ? HallF : HbF[cur ^ 1];
    lstm_step_kernel<32, 36, true, false><<<512, 256, 0, stream>>>(
        XF + (size_t)t * XSLOT, HbF[cur], WpF, bias, CF, hout);
    cur ^= 1;
  }
  // Wp2F aliases XF — build only after warmup consumed XF.
  prep_u_kernel<<<dim3(64, 16), 256, 0, stream>>>(dw, kernelW, recW, Wp2F);

  for (int s = 1; s < OUT_STEPS; ++s) {
    lstm_step_kernel<32, 32, false, false><<<512, 256, 0, stream>>>(
        nullptr, HallF + (size_t)(s - 1) * HSLOT, Wp2F, b2, CF, HallF + (size_t)s * HSLOT);
  }
  dense_allF_kernel<<<(OUT_STEPS * BATCH) / 128, 256, 0, stream>>>(HallF, WdtF, db, out);
}

// Round 8
// 2573.140 us; speedup vs baseline: 1.0670x; 1.0670x over previous
//
#include <hip/hip_runtime.h>
#include <math.h>

#define UNITS 1024
#define FEAT 128
#define TSEQ 48
#define BATCH 2048
#define OUT_STEPS 24
#define N4 4096

typedef unsigned short ushort;
typedef __attribute__((ext_vector_type(8))) short bf16x8;
typedef __attribute__((ext_vector_type(4))) float f32x4;

__device__ __forceinline__ ushort f2bf(float f) {
  unsigned u = __float_as_uint(f);
  unsigned r = (u + 0x7FFF + ((u >> 16) & 1)) >> 16;
  return (ushort)r;
}
__device__ __forceinline__ float sigm(float x) { return 1.0f / (1.0f + __expf(-x)); }
__device__ __forceinline__ float tanh_f(float x) { return 1.0f - 2.0f / (1.0f + __expf(2.0f * x)); }

__device__ __forceinline__ void gload_lds16(const void* g, void* l) {
  __builtin_amdgcn_global_load_lds(
      (const __attribute__((address_space(1))) unsigned int*)g,
      (__attribute__((address_space(3))) unsigned int*)l, 16, 0, 0);
}

// ============ fragment-order conventions (16x16x32 MFMA, verified m89) ============
// A-frag (M=16 rows, K=32): element (row, k) -> lane = ((k>>3)&3)*16 + (row&15), e = k&7
// B-frag (K=32, N=16 cols): element (k, col) -> lane = ((k>>3)&3)*16 + (col&15), e = k&7
// Storage: frag-major arrays F[frag][kc][64][8]: each (frag,kc) slice is 1 KB
// contiguous -> one coalesced load AND a linear global_load_lds destination.

// ---------------- prep kernels ----------------

// inputs [B][T][F] fp32 -> XF [T][128 rf][4 kc][64][8] bf16 (A-fragment order)
__global__ __launch_bounds__(256)
void convert_inputs_kernel(const float* __restrict__ in, ushort* __restrict__ XF) {
  const int g = blockIdx.x * 256 + threadIdx.x;   // ((t*128+rf)*4+kc)*64 + lane
  const int lane = g & 63;
  const int kc = (g >> 6) & 3;
  const int rf = (g >> 8) & 127;
  const int t = g >> 15;
  const int b = rf * 16 + (lane & 15);
  const int f = kc * 32 + ((lane >> 4) & 3) * 8;
  const float* src = &in[((size_t)b * TSEQ + t) * FEAT + f];
  const float4 v0 = *reinterpret_cast<const float4*>(src);
  const float4 v1 = *reinterpret_cast<const float4*>(src + 4);
  ushort v[8];
  v[0] = f2bf(v0.x); v[1] = f2bf(v0.y); v[2] = f2bf(v0.z); v[3] = f2bf(v0.w);
  v[4] = f2bf(v1.x); v[5] = f2bf(v1.y); v[6] = f2bf(v1.z); v[7] = f2bf(v1.w);
  *reinterpret_cast<bf16x8*>(&XF[(size_t)g * 8]) = *reinterpret_cast<bf16x8*>(v);
}

// kernel [128][4096] + recurrent [1024][4096] fp32 -> WpF [256 cf][36 kc][64][8] bf16
// (B-fragment order). Gate-permuted col: np = cf*16 + (lane&15) = ugrp*64+gate*16+u16,
// source col = gate*1024 + ugrp*16 + u16. k = kc*32 + ((lane>>4)&3)*8 + e; k<128 -> kW.
__global__ __launch_bounds__(256)
void prep_wF_kernel(const float* __restrict__ kW, const float* __restrict__ rW,
                    ushort* __restrict__ WpF) {
  const int g = blockIdx.x * 256 + threadIdx.x;   // (cf*36 + kc)*64 + lane
  const int lane = g & 63;
  const int kc = (g >> 6) % 36;
  const int cf = g / 2304;
  const int np = cf * 16 + (lane & 15);
  const int kbase = kc * 32 + ((lane >> 4) & 3) * 8;
  const int u16 = np & 15, gg = (np >> 4) & 3, ugrp = np >> 6;
  const int nsrc = gg * 1024 + ugrp * 16 + u16;
  ushort v[8];
#pragma unroll
  for (int e = 0; e < 8; ++e) {
    const int k = kbase + e;
    const float f = (k < FEAT) ? kW[(size_t)k * N4 + nsrc] : rW[(size_t)(k - FEAT) * N4 + nsrc];
    v[e] = f2bf(f);
  }
  *reinterpret_cast<bf16x8*>(&WpF[(size_t)g * 8]) = *reinterpret_cast<bf16x8*>(v);
}

// dense_w [1024][128] fp32 -> WdtF [8 cf][32 kc][64][8] bf16 (B-fragment order)
__global__ __launch_bounds__(256)
void prep_wdF_kernel(const float* __restrict__ dw, ushort* __restrict__ WdtF) {
  const int g = blockIdx.x * 256 + threadIdx.x;
  const int lane = g & 63;
  const int kc = (g >> 6) & 31;
  const int cf = g >> 11;
  const int col = cf * 16 + (lane & 15);
  const int kb = kc * 32 + ((lane >> 4) & 3) * 8;
  ushort v[8];
#pragma unroll
  for (int e = 0; e < 8; ++e) v[e] = f2bf(dw[(size_t)(kb + e) * FEAT + col]);
  *reinterpret_cast<bf16x8*>(&WdtF[(size_t)g * 8]) = *reinterpret_cast<bf16x8*>(v);
}

// b2[n] = bias[n] + sum_f db[f] * W[f][n]   (original gate order)
__global__ __launch_bounds__(256)
void prep_b2_kernel(const float* __restrict__ bias, const float* __restrict__ db,
                    const float* __restrict__ W, float* __restrict__ b2) {
  const int n = blockIdx.x * 256 + threadIdx.x;
  float s = bias[n];
#pragma unroll 8
  for (int f = 0; f < FEAT; ++f) s += db[f] * W[(size_t)f * N4 + n];
  b2[n] = s;
}

// U' = Wd@W + U -> Wp2F [256 cf][32 kc][64][8] bf16 (B-fragment order)
__global__ __launch_bounds__(256)
void prep_u_kernel(const float* __restrict__ dw,   // [1024][128]
                   const float* __restrict__ W,    // [128][4096]
                   const float* __restrict__ rW,   // [1024][4096]
                   ushort* __restrict__ Wp2F) {
  __shared__ float sWd[64][132];   // [k_local][f]
  __shared__ float sW[128][68];    // [f][n'_local]
  const int tid = threadIdx.x;
  const int ugrp = blockIdx.x;
  const int k0 = blockIdx.y * 64;
  const int n0 = ugrp * 64;

#pragma unroll
  for (int p = 0; p < 8; ++p) {
    const int li = p * 256 + tid;
    const int kk = li >> 5, f4 = (li & 31) * 4;
    *reinterpret_cast<float4*>(&sWd[kk][f4]) =
        *reinterpret_cast<const float4*>(&dw[(size_t)(k0 + kk) * FEAT + f4]);
  }
#pragma unroll
  for (int p = 0; p < 32; ++p) {
    const int li = p * 256 + tid;
    const int f = li >> 6, nn = li & 63;
    const int u16 = nn & 15, gg = (nn >> 4) & 3;
    const int nsrc = gg * 1024 + ugrp * 16 + u16;
    sW[f][nn] = W[(size_t)f * N4 + nsrc];
  }
  __syncthreads();

  const int tx = tid & 15;
  const int ty = tid >> 4;
  float acc[4][4] = {};
  for (int f = 0; f < 128; ++f) {
    float a[4], b[4];
#pragma unroll
    for (int j = 0; j < 4; ++j) a[j] = sWd[tx * 4 + j][f];
#pragma unroll
    for (int i = 0; i < 4; ++i) b[i] = sW[f][ty * 4 + i];
#pragma unroll
    for (int i = 0; i < 4; ++i)
#pragma unroll
      for (int j = 0; j < 4; ++j) acc[i][j] += a[j] * b[i];
  }

#pragma unroll
  for (int i = 0; i < 4; ++i) {
    const int np = n0 + ty * 4 + i;
    const int u16 = np & 15, gg = (np >> 4) & 3;
    const int nsrc = gg * 1024 + ugrp * 16 + u16;
    const int cf = np >> 4;
#pragma unroll
    for (int j = 0; j < 4; ++j) {
      const int k = k0 + tx * 4 + j;
      const float v = rW[(size_t)k * N4 + nsrc] + acc[i][j];
      const int kc = k >> 5, lane = ((k >> 3) & 3) * 16 + (np & 15), e = k & 7;
      Wp2F[(((size_t)cf * 32 + kc) * 64 + lane) * 8 + e] = f2bf(v);
    }
  }
}

// ---------------- fused LSTM step: 256x128 tile, L2-traffic-minimal ----------------
// Grid 256 blocks (1/CU) x 256 threads (4 waves of 128x64). A and B both staged
// via global_load_lds from fragment-ordered arrays (linear dest, conflict-free
// lane-contiguous ds_read_b128). 2-deep prefetch, 3 LDS buffers, per-wave counted
// vmcnt (6 loads/iter -> vmcnt(12) steady, 6/0 tail), raw barriers, setprio.
// NT: # of 32-wide K chunks; NKS: WF kc-stride; HASX: kc 0..3 from X; ZC: c==0.
template<int NT, int NKS, bool HASX, bool ZC>
__global__ __launch_bounds__(256)
void lstm_step_kernel(const ushort* __restrict__ XF,    // [128 rf][4][512] (this t)
                      const ushort* __restrict__ HF,    // [128 rf][32][512]
                      const ushort* __restrict__ WF,    // [256 cf][NKS][512]
                      const float* __restrict__ bias,   // [4096] fp32, orig gate order
                      float* __restrict__ CF,           // [128 rf][64 U][64 l][4]
                      ushort* __restrict__ HoutF) {     // [128 rf][32][512]
  __shared__ alignas(16) ushort sL[3 * 12288];  // 3 bufs: A 16KB + B 8KB each

  const int bid = blockIdx.x;
  const int wg = (bid & 7) * 32 + (bid >> 3);   // bijective XCD chunk swizzle (256%8==0)
  const int bx = wg >> 5;                       // 0..7  : rows bx*256
  const int by = wg & 31;                       // 0..31 : cols by*128 (8 col-frags)

  const int tid = threadIdx.x;
  const int wid = tid >> 6;
  const int l = tid & 63;
  const int wr = wid >> 1;     // 0..1: rows wr*128 within tile
  const int wc = wid & 1;      // 0..1: cols wc*64
  const int l15 = l & 15, kg = l >> 4;

  f32x4 acc[8][4] = {};

  // stage one K-chunk (kc = t): 16 A chunks (1 KB) + 8 B chunks; 6 per wave.
  auto STAGE = [&](int t, int bufi) {
    ushort* base = &sL[bufi * 12288];
#pragma unroll
    for (int q = 0; q < 6; ++q) {
      const int c = wid * 6 + q;    // 0..23
      const ushort* src;
      ushort* dst;
      if (c < 16) {
        const int rf = bx * 16 + c;
        if (HASX && t < 4) src = XF + ((size_t)rf * 4 + t) * 512;
        else               src = HF + ((size_t)rf * 32 + (t - (HASX ? 4 : 0))) * 512;
        dst = base + c * 512;
      } else {
        src = WF + ((size_t)(by * 8 + (c - 16)) * NKS + t) * 512;
        dst = base + 8192 + (c - 16) * 512;
      }
      gload_lds16(src + (size_t)l * 8, dst);
    }
  };

  STAGE(0, 0);
  STAGE(1, 1);

  for (int t = 0; t < NT; ++t) {
    const int bi = t % 3;
    if (t + 2 < NT) {
      STAGE(t + 2, (t + 2) % 3);
      asm volatile("s_waitcnt vmcnt(12)" ::: "memory");
    } else if (t + 1 < NT) {
      asm volatile("s_waitcnt vmcnt(6)" ::: "memory");
    } else {
      asm volatile("s_waitcnt vmcnt(0)" ::: "memory");
    }
    __builtin_amdgcn_s_barrier();

    const ushort* bA = &sL[bi * 12288];
    const ushort* bB = bA + 8192;
    bf16x8 av[8], bv[4];
#pragma unroll
    for (int n = 0; n < 4; ++n)
      bv[n] = *reinterpret_cast<const bf16x8*>(bB + (wc * 4 + n) * 512 + l * 8);
#pragma unroll
    for (int m = 0; m < 8; ++m)
      av[m] = *reinterpret_cast<const bf16x8*>(bA + (wr * 8 + m) * 512 + l * 8);

    __builtin_amdgcn_s_setprio(1);
#pragma unroll
    for (int m = 0; m < 8; ++m)
#pragma unroll
      for (int n = 0; n < 4; ++n)
        acc[m][n] = __builtin_amdgcn_mfma_f32_16x16x32_bf16(av[m], bv[n], acc[m][n], 0, 0, 0);
    __builtin_amdgcn_s_setprio(0);
    __builtin_amdgcn_s_barrier();
  }

  // ---- epilogue: gates + state update; h written in A-fragment order ----
  const int U = by * 2 + wc;            // unit-group 0..63
  const int unit = U * 16 + l15;
  const float bi_ = bias[unit];
  const float bf_ = bias[1024 + unit];
  const float bg = bias[2048 + unit];
  const float bo = bias[3072 + unit];

  const int kcu = unit >> 5;                 // h-fragment kc of this unit
  const int lxb = ((unit >> 3) & 3) * 16;    // h-fragment lane base
  const int eu = unit & 7;                   // h-fragment elem

#pragma unroll
  for (int m = 0; m < 8; ++m) {
    const int rf = bx * 16 + wr * 8 + m;
    const size_t cfidx = (((size_t)rf * 64 + U) * 64 + l) * 4;
    f32x4 cpre;
    if (!ZC) cpre = *reinterpret_cast<const f32x4*>(CF + cfidx);
    const size_t hfrag = ((size_t)rf * 32 + kcu) * 64;
    f32x4 cout;
#pragma unroll
    for (int j = 0; j < 4; ++j) {
      const float i_ = sigm(acc[m][0][j] + bi_);
      const float f_ = sigm(acc[m][1][j] + bf_);
      const float g_ = tanh_f(acc[m][2][j] + bg);
      const float o_ = sigm(acc[m][3][j] + bo);
      const float cn = ZC ? (i_ * g_) : (f_ * cpre[j] + i_ * g_);
      cout[j] = cn;
      HoutF[(hfrag + lxb + kg * 4 + j) * 8 + eu] = f2bf(o_ * tanh_f(cn));
    }
    *reinterpret_cast<f32x4*>(CF + cfidx) = cout;
  }
}

// ---------------- batched dense (register-direct): out = HallF @ Wd + db ----------------
__global__ __launch_bounds__(256, 2)
void dense_allF_kernel(const ushort* __restrict__ HallF,  // [3072 rf][32][512]
                       const ushort* __restrict__ WdtF,   // [8 cf][32][512]
                       const float* __restrict__ db,
                       float* __restrict__ out) {         // [2048][24][128] fp32
  const int bid = blockIdx.x;    // 384
  const int tid = threadIdx.x;
  const int wid = tid >> 6;
  const int l = tid & 63;
  const int wr = wid >> 1, wc = wid & 1;
  const int l15 = l & 15, kg = l >> 4;
  const int rfb = bid * 8 + wr * 4;
  const int cfb = wc * 4;

  f32x4 acc[4][4] = {};

#pragma unroll 4
  for (int kc = 0; kc < 32; ++kc) {
    bf16x8 av[4], bv[4];
#pragma unroll
    for (int m = 0; m < 4; ++m)
      av[m] = *reinterpret_cast<const bf16x8*>(
          HallF + (((size_t)(rfb + m) * 32 + kc) * 64 + l) * 8);
#pragma unroll
    for (int n = 0; n < 4; ++n)
      bv[n] = *reinterpret_cast<const bf16x8*>(
          WdtF + (((size_t)(cfb + n) * 32 + kc) * 64 + l) * 8);
#pragma unroll
    for (int m = 0; m < 4; ++m)
#pragma unroll
      for (int n = 0; n < 4; ++n)
        acc[m][n] = __builtin_amdgcn_mfma_f32_16x16x32_bf16(av[m], bv[n], acc[m][n], 0, 0, 0);
  }

#pragma unroll
  for (int n = 0; n < 4; ++n) {
    const int col = (cfb + n) * 16 + l15;
    const float bb = db[col];
#pragma unroll
    for (int m = 0; m < 4; ++m) {
#pragma unroll
      for (int j = 0; j < 4; ++j) {
        const int row = bid * 128 + wr * 64 + m * 16 + kg * 4 + j;
        const int s = row >> 11, b = row & 2047;
        out[((size_t)b * OUT_STEPS + s) * FEAT + col] = acc[m][n][j] + bb;
      }
    }
  }
}

// ---------------- launch ----------------
extern "C" void kernel_launch(void* const* d_in, const int* in_sizes, int n_in,
                              void* d_out, int out_size, void* d_ws, size_t ws_size,
                              hipStream_t stream) {
  const float* inputs  = (const float*)d_in[0];
  const float* kernelW = (const float*)d_in[1];
  const float* recW    = (const float*)d_in[2];
  const float* bias    = (const float*)d_in[3];
  const float* dw      = (const float*)d_in[4];
  const float* db      = (const float*)d_in[5];
  float* out = (float*)d_out;

  char* ws = (char*)d_ws;
  float*  CF    = (float*)ws;                                   // 8 MB
  ushort* XF    = (ushort*)(ws + 8388608);                      // 24 MB (warmup only)
  ushort* Wp2F  = XF;                                           // 8 MB, aliases XF
  ushort* HbF0  = (ushort*)(ws + 33554432);                     // 4 MB
  ushort* HbF1  = (ushort*)(ws + 37748736);                     // 4 MB
  ushort* WpF   = (ushort*)(ws + 41943040);                     // 9 MB
  ushort* WdtF  = (ushort*)(ws + 51380224);                     // 256 KB
  float*  b2    = (float*)(ws + 51642368);                      // 16 KB
  ushort* HallF = (ushort*)(ws + 51658752);                     // 96 MB: [24][128][32][512]
  ushort* HbF[2] = {HbF0, HbF1};
  const size_t HSLOT = (size_t)128 * 32 * 512;                  // ushorts per h snapshot
  const size_t XSLOT = (size_t)128 * 4 * 512;                   // ushorts per x timestep

  convert_inputs_kernel<<<TSEQ * 128 * 4 * 64 / 256, 256, 0, stream>>>(inputs, XF);
  prep_wF_kernel<<<256 * 36 * 64 / 256, 256, 0, stream>>>(kernelW, recW, WpF);
  prep_wdF_kernel<<<8 * 32 * 64 / 256, 256, 0, stream>>>(dw, WdtF);
  prep_b2_kernel<<<N4 / 256, 256, 0, stream>>>(bias, db, kernelW, b2);

  // t = 0: c = h = 0 -> x-part only (NT=4), no C read, no memsets.
  lstm_step_kernel<4, 36, true, true><<<256, 256, 0, stream>>>(
      XF, HbF0 /*unused*/, WpF, bias, CF, HbF1);
  int cur = 1;
  for (int t = 1; t < TSEQ; ++t) {
    ushort* hout = (t == TSEQ - 1) ? HallF : HbF[cur ^ 1];
    lstm_step_kernel<36, 36, true, false><<<256, 256, 0, stream>>>(
        XF + (size_t)t * XSLOT, HbF[cur], WpF, bias, CF, hout);
    cur ^= 1;
  }
  // Wp2F aliases XF — build only after warmup consumed XF.
  prep_u_kernel<<<dim3(64, 16), 256, 0, stream>>>(dw, kernelW, recW, Wp2F);

  for (int s = 1; s < OUT_STEPS; ++s) {
    lstm_step_kernel<32, 32, false, false><<<256, 256, 0, stream>>>(
        nullptr, HallF + (size_t)(s - 1) * HSLOT, Wp2F, b2, CF, HallF + (size_t)s * HSLOT);
  }
  dense_allF_kernel<<<(OUT_STEPS * BATCH) / 128, 256, 0, stream>>>(HallF, WdtF, db, out);
}